// Round 10
// baseline (77.256 us; speedup 1.0000x reference)
//
#include <hip/hip_runtime.h>
#include <math.h>

#define NUM_ENT 10000
#define NUM_REL 230
#define R2      460
#define S_DIM   96
#define T_DIM   32
#define DIM     128
#define N_NBR   32768
#define Q_ENT   4096
#define E_EDGE  32768
#define B_TRI   1024
#define BN_EPS  1e-5f
#define CHUNK   64

typedef __attribute__((ext_vector_type(8))) short bf16x8;
typedef __attribute__((ext_vector_type(4))) float f32x4;

// f32 -> bf16 round-to-nearest-even
__device__ __forceinline__ unsigned short f2bf(float f) {
    unsigned int u = __float_as_uint(f);
    u = (u + 0x7FFFu + ((u >> 16) & 1u)) >> 16;
    return (unsigned short)u;
}

// X LDS swizzle (ushort units): breaks the 256B row stride for A-frag b128
// reads. XOR bits >=3 keep 4-ushort groups contiguous (8B stores ok).
__device__ __forceinline__ int XIDX(int m, int d) {
    return (m * DIM + d) ^ ((m & 7) << 3);
}

// W f32 staging swizzle (float units, row k in [0,64), col n in [0,128)):
// XOR bits 2..4 of the column with (k&7) and (k>>3)&3 so that the
// fragment-order conversion reads (8 rows x same col, 4 row-groups) hit
// 32 distinct banks (2-way = free). float4 alignment preserved.
__device__ __forceinline__ int WSIDX(int k, int n) {
    return k * DIM + (n ^ ((k & 7) << 2) ^ (((k >> 3) & 3) << 3));
}

// ---------------------------------------------------------------------------
// K0: zero hist_rel(460)+hist_dst(4096) = 4556 ints (1139 int4)
// ---------------------------------------------------------------------------
__global__ void k_zero(int* __restrict__ p, int n4) {
    int i = blockIdx.x * blockDim.x + threadIdx.x;
    if (i < n4) ((int4*)p)[i] = make_int4(0, 0, 0, 0);
}

// ---------------------------------------------------------------------------
// K1: parallel histograms: rel_id -> 460 bins, pool_dst -> 4096 bins
// ---------------------------------------------------------------------------
__global__ void k_hist(const int* __restrict__ rel, const int* __restrict__ pdst,
                       int* __restrict__ hist_rel, int* __restrict__ hist_dst) {
    int i = blockIdx.x * blockDim.x + threadIdx.x;
    if (i < N_NBR) atomicAdd(&hist_rel[rel[i]], 1);
    if (i < E_EDGE) atomicAdd(&hist_dst[pdst[i]], 1);
}

// ---------------------------------------------------------------------------
// K2: fused scans (2 blocks x 1024 thr). Block 0: rel hist -> offsets[461],
// cursor init cur_rel. Block 1: dst hist -> dst_off[4097], cursor cur_dst.
// ---------------------------------------------------------------------------
__global__ void k_scan_both(const int* __restrict__ hist_rel, int* __restrict__ offsets,
                            int* __restrict__ cur_rel,
                            const int* __restrict__ hist_dst, int* __restrict__ dst_off,
                            int* __restrict__ cur_dst)
{
    __shared__ int s[1024];
    const int t = threadIdx.x;
    if (blockIdx.x == 0) {
        const int h = (t < R2) ? hist_rel[t] : 0;
        if (t < 512) s[t] = h;
        __syncthreads();
        for (int off = 1; off < 512; off <<= 1) {
            int a = (t >= off && t < 512) ? s[t - off] : 0;
            __syncthreads();
            if (t < 512) s[t] += a;
            __syncthreads();
        }
        if (t == 0) offsets[0] = 0;
        if (t < R2) {
            offsets[t + 1] = s[t];      // inclusive
            cur_rel[t] = s[t] - h;      // exclusive
        }
    } else {
        const int base = t * 4;
        int v0 = hist_dst[base], v1 = hist_dst[base + 1];
        int v2 = hist_dst[base + 2], v3 = hist_dst[base + 3];
        s[t] = v0 + v1 + v2 + v3;
        __syncthreads();
        for (int off = 1; off < 1024; off <<= 1) {
            int a = (t >= off) ? s[t - off] : 0;
            __syncthreads();
            s[t] += a;
            __syncthreads();
        }
        int run = (t > 0) ? s[t - 1] : 0;
        dst_off[base] = run; cur_dst[base] = run; run += v0;
        dst_off[base + 1] = run; cur_dst[base + 1] = run; run += v1;
        dst_off[base + 2] = run; cur_dst[base + 2] = run; run += v2;
        dst_off[base + 3] = run; cur_dst[base + 3] = run; run += v3;
        if (t == 1023) dst_off[4096] = run;
    }
}

// ---------------------------------------------------------------------------
// K3: scatter. rel-sorted neighbor order; rankpack[i] = row | (rel<<17);
// dst-sorted edge list stores the SOURCE NEIGHBOR ID directly.
// ---------------------------------------------------------------------------
__global__ void k_scatter(const int* __restrict__ rel,
                          int* __restrict__ cur_rel, int* __restrict__ order,
                          int* __restrict__ rankpack,
                          const int* __restrict__ psrc, const int* __restrict__ pdst,
                          int* __restrict__ cur_dst, int* __restrict__ eorder_src) {
    int i = blockIdx.x * blockDim.x + threadIdx.x;
    if (i < N_NBR) {
        const int r = rel[i];
        const int pos = atomicAdd(&cur_rel[r], 1);
        order[pos] = i;
        rankpack[i] = pos | (r << 17);
    }
    if (i < E_EDGE) {
        eorder_src[atomicAdd(&cur_dst[pdst[i]], 1)] = psrc[i];
    }
}

// ---------------------------------------------------------------------------
// K4: MFMA matvec. ONE BLOCK (512 thr = 8 waves) PER RELATION.
// PROLOGUE: block converts its own W[r] f32 -> bf16 MFMA-fragment order
//   directly into LDS Wl (32 KB), two passes of 32 KB f32 staged in the Xl
//   region (coalesced float4 reads, bank-swizzled). No global Wfrag buffer.
// MAIN LOOP: 8 waves process TWO 64-row chunks concurrently (half = wid>>2).
//   X gathered as bf16 into swizzled LDS [2][64][128]. B-frags = conflict-
//   free b128 LDS reads from Wl. BN stats in registers, cross-half combine
//   via LDS; block emits per-(rel,col) scale/shift to global (z_s stays raw).
// LDS ~67 KB -> 2 blocks/CU (grid 460 on 256 CUs = 1.8/CU, no loss).
// ---------------------------------------------------------------------------
__global__ __launch_bounds__(512, 4) void k_matvec(
    const int* __restrict__ order, const int* __restrict__ offsets,
    const int* __restrict__ nbr,
    const float* __restrict__ years, const float* __restrict__ months, const float* __restrict__ days,
    const float* __restrict__ ent,
    const float* __restrict__ yf, const float* __restrict__ yp, const float* __restrict__ ya,
    const float* __restrict__ mf, const float* __restrict__ mp, const float* __restrict__ ma,
    const float* __restrict__ df, const float* __restrict__ dp, const float* __restrict__ da,
    const float* __restrict__ W, const float* __restrict__ bias,
    const float* __restrict__ gamma, const float* __restrict__ beta,
    float* __restrict__ z_s, float* __restrict__ scale, float* __restrict__ shift)
{
    const int r     = blockIdx.x;
    const int start = offsets[r];
    const int cnt   = offsets[r + 1] - start;

    __shared__ __align__(16) unsigned short Wl[DIM * DIM];       // 32 KB bf16 frags
    __shared__ __align__(16) unsigned short Xl[2][CHUNK * DIM];  // 32 KB (stage/X)
    __shared__ int s_ord[2][CHUNK];
    __shared__ int s_ni[2][CHUNK];
    __shared__ float bnred[8][2][16][2];   // [wid][nt][l15][sum|sq]

    const int t    = threadIdx.x;
    const int wid  = t >> 6;        // 0..7
    const int half = wid >> 2;      // 0,1 : which chunk of the pair
    const int wv   = wid & 3;       // column group
    const int lane = t & 63;
    const int l15  = lane & 15;
    const int g    = lane >> 4;

    // ---- PROLOGUE: W[r] f32 -> bf16 fragment order in Wl (two 32 KB passes)
    {
        float* Xf = (float*)&Xl[0][0];   // 8192 floats staging
        #pragma unroll
        for (int p = 0; p < 2; ++p) {
            const float4* Wg = (const float4*)(W + (size_t)r * DIM * DIM + p * 8192);
            #pragma unroll
            for (int i = 0; i < 4; ++i) {
                const int c  = t + i * 512;     // float4 index 0..2047
                const int k  = c >> 5;          // row within half (0..63)
                const int n4 = (c & 31) * 4;
                *(float4*)&Xf[WSIDX(k, n4)] = Wg[c];
            }
            __syncthreads();
            #pragma unroll
            for (int i = 0; i < 2; ++i) {
                const int id  = t + i * 512;        // slot within pass: 0..1023
                const int sid = p * 1024 + id;      // global slot 0..2047
                const int sl  = sid & 63;
                const int sh_ = (sid >> 6) & 1;
                const int swv = (sid >> 7) & 3;
                const int skk = (sid >> 9) & 3;
                const int n   = 32 * swv + 16 * sh_ + (sl & 15);
                const int kbl = 32 * skk + 8 * (sl >> 4) - 64 * p;  // 0..56
                const int sg  = sl >> 4;
                ushort4 lo, hi;
                lo.x = f2bf(Xf[(kbl + 0) * DIM + (n ^ 0  ^ (sg << 3))]);
                lo.y = f2bf(Xf[(kbl + 1) * DIM + (n ^ 4  ^ (sg << 3))]);
                lo.z = f2bf(Xf[(kbl + 2) * DIM + (n ^ 8  ^ (sg << 3))]);
                lo.w = f2bf(Xf[(kbl + 3) * DIM + (n ^ 12 ^ (sg << 3))]);
                hi.x = f2bf(Xf[(kbl + 4) * DIM + (n ^ 16 ^ (sg << 3))]);
                hi.y = f2bf(Xf[(kbl + 5) * DIM + (n ^ 20 ^ (sg << 3))]);
                hi.z = f2bf(Xf[(kbl + 6) * DIM + (n ^ 24 ^ (sg << 3))]);
                hi.w = f2bf(Xf[(kbl + 7) * DIM + (n ^ 28 ^ (sg << 3))]);
                *(ushort4*)&Wl[sid * 8]     = lo;
                *(ushort4*)&Wl[sid * 8 + 4] = hi;
            }
            __syncthreads();
        }
    }

    const int nn0 = 32 * wv + l15;
    const int nn1 = nn0 + 16;
    const float bv0 = bias[r * DIM + nn0];
    const float bv1 = bias[r * DIM + nn1];

    float lsum0 = 0.f, lsq0 = 0.f, lsum1 = 0.f, lsq1 = 0.f;

    for (int cbase = 0; cbase < cnt; cbase += 2 * CHUNK) {
        const int hbase = cbase + half * CHUNK;
        const int mcnt  = min(CHUNK, max(0, cnt - hbase));

        if (t < 2 * CHUNK) {
            const int hh = t >> 6;   // half being staged
            const int m  = t & 63;
            const int gb = cbase + hh * CHUNK;
            int o = -1, ni = 0;
            if (gb + m < cnt) { o = order[start + gb + m]; ni = nbr[o]; }
            s_ord[hh][m] = o;
            s_ni[hh][m]  = ni;
        }
        __syncthreads();

        // ---- gather X for this half (256 threads): 4 thr/row
        if (mcnt > 0) {
            const int lt = t & 255;
            const int m = lt >> 2, s = lt & 3;
            const int ni = s_ni[half][m];
            const bool vm = (m < mcnt);
            #pragma unroll
            for (int kk = 0; kk < 6; ++kk) {
                const int d = 4 * (s + 4 * kk);
                float4 e = *(const float4*)(ent + (size_t)ni * S_DIM + d);
                ushort4 b;
                b.x = vm ? f2bf(e.x) : 0; b.y = vm ? f2bf(e.y) : 0;
                b.z = vm ? f2bf(e.z) : 0; b.w = vm ? f2bf(e.w) : 0;
                *(ushort4*)&Xl[half][XIDX(m, d)] = b;
            }
            const int o = s_ord[half][m] < 0 ? 0 : s_ord[half][m];
            const float yr = years[o], mo = months[o], dy = days[o];
            #pragma unroll
            for (int hh = 0; hh < 2; ++hh) {
                const int j0 = s * 8 + hh * 4;
                const size_t tb = (size_t)ni * T_DIM + j0;
                const float4 vyf = *(const float4*)(yf + tb), vyp = *(const float4*)(yp + tb), vya = *(const float4*)(ya + tb);
                const float4 vmf = *(const float4*)(mf + tb), vmp = *(const float4*)(mp + tb), vma = *(const float4*)(ma + tb);
                const float4 vdf = *(const float4*)(df + tb), vdp = *(const float4*)(dp + tb), vda = *(const float4*)(da + tb);
                ushort4 b;
                #pragma unroll
                for (int j = 0; j < 4; ++j) {
                    const float fy = ((const float*)&vyf)[j] * yr + ((const float*)&vyp)[j];
                    const float fm = ((const float*)&vmf)[j] * mo + ((const float*)&vmp)[j];
                    const float fd = ((const float*)&vdf)[j] * dy + ((const float*)&vdp)[j];
                    float v = ((const float*)&vya)[j] * sinf(fy)
                            + ((const float*)&vma)[j] * sinf(fm)
                            + ((const float*)&vda)[j] * sinf(fd);
                    ((unsigned short*)&b)[j] = vm ? f2bf(v) : 0;
                }
                *(ushort4*)&Xl[half][XIDX(m, S_DIM + j0)] = b;
            }
        }
        __syncthreads();

        // ---- MFMA + epilogue for this half
        if (mcnt > 0) {
            f32x4 acc[4][2];
            #pragma unroll
            for (int i = 0; i < 4; ++i)
                #pragma unroll
                for (int j = 0; j < 2; ++j) acc[i][j] = (f32x4)0.f;

            #pragma unroll
            for (int kk = 0; kk < 4; ++kk) {
                const int k0 = kk * 32;
                bf16x8 a[4];
                #pragma unroll
                for (int mt = 0; mt < 4; ++mt)
                    a[mt] = *(const bf16x8*)&Xl[half][XIDX(16 * mt + l15, k0 + 8 * g)];
                const bf16x8 b0 = *(const bf16x8*)&Wl[((kk * 4 + wv) * 2 + 0) * 512 + lane * 8];
                const bf16x8 b1 = *(const bf16x8*)&Wl[((kk * 4 + wv) * 2 + 1) * 512 + lane * 8];
                #pragma unroll
                for (int mt = 0; mt < 4; ++mt) {
                    acc[mt][0] = __builtin_amdgcn_mfma_f32_16x16x32_bf16(a[mt], b0, acc[mt][0], 0, 0, 0);
                    acc[mt][1] = __builtin_amdgcn_mfma_f32_16x16x32_bf16(a[mt], b1, acc[mt][1], 0, 0, 0);
                }
            }

            #pragma unroll
            for (int mt = 0; mt < 4; ++mt) {
                #pragma unroll
                for (int reg = 0; reg < 4; ++reg) {
                    const int ml = 16 * mt + 4 * g + reg;
                    if (ml < mcnt) {
                        const float v0 = acc[mt][0][reg] + bv0;
                        const float v1 = acc[mt][1][reg] + bv1;
                        const size_t row = (size_t)(start + hbase + ml) * DIM;
                        z_s[row + nn0] = v0;
                        z_s[row + nn1] = v1;
                        lsum0 += v0; lsq0 += v0 * v0;
                        lsum1 += v1; lsq1 += v1 * v1;
                    }
                }
            }
        }
        __syncthreads();
    }

    // ---- BN fold: intra-wave (over g), then cross-half via LDS -> global
    lsum0 += __shfl_xor(lsum0, 16); lsum0 += __shfl_xor(lsum0, 32);
    lsq0  += __shfl_xor(lsq0, 16);  lsq0  += __shfl_xor(lsq0, 32);
    lsum1 += __shfl_xor(lsum1, 16); lsum1 += __shfl_xor(lsum1, 32);
    lsq1  += __shfl_xor(lsq1, 16);  lsq1  += __shfl_xor(lsq1, 32);
    if (g == 0) {
        bnred[wid][0][l15][0] = lsum0; bnred[wid][0][l15][1] = lsq0;
        bnred[wid][1][l15][0] = lsum1; bnred[wid][1][l15][1] = lsq1;
    }
    __syncthreads();
    if (half == 0 && g == 0) {
        #pragma unroll
        for (int nt = 0; nt < 2; ++nt) {
            const int col = 32 * wv + 16 * nt + l15;
            const float s = bnred[wid][nt][l15][0] + bnred[wid + 4][nt][l15][0];
            const float q = bnred[wid][nt][l15][1] + bnred[wid + 4][nt][l15][1];
            float sc = 1.f, sh = 0.f;
            if (cnt > 1) {
                const float mean = s / (float)cnt;
                const float var  = fmaxf(q / (float)cnt - mean * mean, 0.f);
                const int gi = r * DIM + col;
                sc = gamma[gi] * rsqrtf(var + BN_EPS);
                sh = beta[gi] - mean * sc;
            }
            scale[r * DIM + col] = sc;
            shift[r * DIM + col] = sh;
        }
    }
}

// ---------------------------------------------------------------------------
// K5: pooling with fused BN affine + ReLU. One block per query; chain:
// eorder_src[e] -> rankpack -> {z_s row, scale/shift (L2-hot)}.
// ---------------------------------------------------------------------------
__global__ void k_pool2(const int* __restrict__ eorder_src, const int* __restrict__ dst_off,
                        const int* __restrict__ rankpack,
                        const float* __restrict__ z_s,
                        const float* __restrict__ scale, const float* __restrict__ shift,
                        float* __restrict__ emb)
{
    const int q = blockIdx.x;
    const int d = threadIdx.x;
    const int e0 = dst_off[q], e1 = dst_off[q + 1];
    float acc = 0.f;
    for (int e = e0; e < e1; ++e) {
        const int pk = rankpack[eorder_src[e]];
        const int p  = pk & 0x1FFFF;
        const int r  = pk >> 17;
        const float v = z_s[(size_t)p * DIM + d] * scale[r * DIM + d] + shift[r * DIM + d];
        acc += fmaxf(v, 0.f);
    }
    emb[(size_t)q * DIM + d] = (e1 > e0) ? acc / (float)(e1 - e0) : 0.f;
}

// ---------------------------------------------------------------------------
// K6: TransE scoring
// ---------------------------------------------------------------------------
__global__ void k_score(const int* __restrict__ head, const int* __restrict__ tail,
                        const int* __restrict__ rels,
                        const float* __restrict__ emb, const float* __restrict__ rel_embs,
                        float* __restrict__ out)
{
    const int b = blockIdx.x;
    const int d = threadIdx.x;
    const int h = head[b], tq = tail[b], r = rels[b];

    const float diff = emb[(size_t)h * DIM + d] + rel_embs[r * DIM + d]
                     - emb[(size_t)tq * DIM + d];
    float sq = diff * diff;
    for (int off = 32; off > 0; off >>= 1) sq += __shfl_down(sq, off);
    __shared__ float partial[2];
    if ((threadIdx.x & 63) == 0) partial[threadIdx.x >> 6] = sq;
    __syncthreads();
    if (threadIdx.x == 0) out[b] = -sqrtf(partial[0] + partial[1]);
}

// ---------------------------------------------------------------------------
extern "C" void kernel_launch(void* const* d_in, const int* in_sizes, int n_in,
                              void* d_out, int out_size, void* d_ws, size_t ws_size,
                              hipStream_t stream) {
    const int*   neighbor_idx = (const int*)  d_in[0];
    const int*   rel_id       = (const int*)  d_in[1];
    const float* years        = (const float*)d_in[2];
    const float* months       = (const float*)d_in[3];
    const float* days         = (const float*)d_in[4];
    const int*   pool_src     = (const int*)  d_in[5];
    const int*   pool_dst     = (const int*)  d_in[6];
    const int*   head_pos     = (const int*)  d_in[7];
    const int*   tail_pos     = (const int*)  d_in[8];
    const int*   rels         = (const int*)  d_in[9];
    const float* ent_embs     = (const float*)d_in[10];
    const float* y_freq       = (const float*)d_in[11];
    const float* y_phi        = (const float*)d_in[12];
    const float* y_amp        = (const float*)d_in[13];
    const float* m_freq       = (const float*)d_in[14];
    const float* m_phi        = (const float*)d_in[15];
    const float* m_amp        = (const float*)d_in[16];
    const float* d_freq       = (const float*)d_in[17];
    const float* d_phi        = (const float*)d_in[18];
    const float* d_amp        = (const float*)d_in[19];
    const float* rel_embs     = (const float*)d_in[20];
    const float* W            = (const float*)d_in[21];
    const float* bias         = (const float*)d_in[22];
    const float* gamma        = (const float*)d_in[23];
    const float* beta         = (const float*)d_in[24];

    float* out = (float*)d_out;

    // workspace layout (float units)
    float* ws = (float*)d_ws;
    size_t off = 0;
    float* z_s   = ws + off; off += (size_t)N_NBR * DIM;   // 16 MB
    float* emb   = ws + off; off += (size_t)Q_ENT * DIM;
    float* scale = ws + off; off += (size_t)R2 * DIM;
    float* shift = ws + off; off += (size_t)R2 * DIM;
    int* hist_rel = (int*)(ws + off); off += R2;       // zero region (4556 ints)
    int* hist_dst = (int*)(ws + off); off += Q_ENT;
    int* offsets  = (int*)(ws + off); off += R2 + 1;
    int* cur_rel  = (int*)(ws + off); off += R2;
    int* dst_off  = (int*)(ws + off); off += Q_ENT + 1;
    int* cur_dst  = (int*)(ws + off); off += Q_ENT;
    int* order    = (int*)(ws + off); off += N_NBR;
    int* rankpack = (int*)(ws + off); off += N_NBR;
    int* eorder_src = (int*)(ws + off); off += E_EDGE;

    const int nzero4 = (R2 + Q_ENT + 3) / 4;   // 1139 int4
    k_zero<<<(nzero4 + 255) / 256, 256, 0, stream>>>(hist_rel, nzero4);

    k_hist<<<(N_NBR + 255) / 256, 256, 0, stream>>>(rel_id, pool_dst, hist_rel, hist_dst);

    k_scan_both<<<2, 1024, 0, stream>>>(hist_rel, offsets, cur_rel,
                                        hist_dst, dst_off, cur_dst);

    k_scatter<<<(N_NBR + 255) / 256, 256, 0, stream>>>(rel_id, cur_rel, order, rankpack,
                                                       pool_src, pool_dst, cur_dst, eorder_src);

    k_matvec<<<R2, 512, 0, stream>>>(order, offsets, neighbor_idx,
                                     years, months, days, ent_embs,
                                     y_freq, y_phi, y_amp,
                                     m_freq, m_phi, m_amp,
                                     d_freq, d_phi, d_amp,
                                     W, bias, gamma, beta,
                                     z_s, scale, shift);

    k_pool2<<<Q_ENT, DIM, 0, stream>>>(eorder_src, dst_off, rankpack,
                                       z_s, scale, shift, emb);

    k_score<<<B_TRI, DIM, 0, stream>>>(head_pos, tail_pos, rels, emb, rel_embs, out);
}

// Round 13
// 75.780 us; speedup vs baseline: 1.0195x; 1.0195x over previous
//
#include <hip/hip_runtime.h>
#include <math.h>

#define NUM_ENT 10000
#define NUM_REL 230
#define R2      460
#define S_DIM   96
#define T_DIM   32
#define DIM     128
#define N_NBR   32768
#define Q_ENT   4096
#define E_EDGE  32768
#define B_TRI   1024
#define BN_EPS  1e-5f
#define CHUNK   64

typedef __attribute__((ext_vector_type(8))) short bf16x8;
typedef __attribute__((ext_vector_type(4))) float f32x4;

// f32 -> bf16 round-to-nearest-even
__device__ __forceinline__ unsigned short f2bf(float f) {
    unsigned int u = __float_as_uint(f);
    u = (u + 0x7FFFu + ((u >> 16) & 1u)) >> 16;
    return (unsigned short)u;
}
__device__ __forceinline__ float bf2f(unsigned short us) {
    return __uint_as_float((unsigned int)us << 16);
}

// X LDS swizzle (ushort units): breaks the 256B row stride for A-frag b128
// reads. XOR bits >=3 keep 4-ushort groups contiguous (8B stores ok).
__device__ __forceinline__ int XIDX(int m, int d) {
    return (m * DIM + d) ^ ((m & 7) << 3);
}

// ---------------------------------------------------------------------------
// K0: zero hist_rel(460)+hist_dst(4096) = 4556 ints (1139 int4)
// ---------------------------------------------------------------------------
__global__ void k_zero(int* __restrict__ p, int n4) {
    int i = blockIdx.x * blockDim.x + threadIdx.x;
    if (i < n4) ((int4*)p)[i] = make_int4(0, 0, 0, 0);
}

// ---------------------------------------------------------------------------
// K1: blocks [0,460): W[r] f32 -> bf16 in per-lane MFMA fragment order.
//   Wfrag ushort offset: ((kk*4+wv)*2+h)*512 + lane*8 + j holds
//   bf16(W[r][32*kk + 8*(lane>>4) + j][32*wv + 16*h + (lane&15)]).
// blocks [460,588): PARALLEL histograms (global atomics into zeroed bufs).
// ---------------------------------------------------------------------------
__global__ __launch_bounds__(256, 2) void k_front(
    const float* __restrict__ W, unsigned short* __restrict__ Wfrag,
    const int* __restrict__ rel, const int* __restrict__ pdst,
    int* __restrict__ hist_rel, int* __restrict__ hist_dst)
{
    const int t = threadIdx.x;
    if (blockIdx.x >= R2) {
        const int i = (blockIdx.x - R2) * 256 + t;
        if (i < N_NBR) atomicAdd(&hist_rel[rel[i]], 1);
        if (i < E_EDGE) atomicAdd(&hist_dst[pdst[i]], 1);
        return;
    }
    const int r = blockIdx.x;
    __shared__ float Wl[DIM * DIM];   // 64 KB
    {
        const float4* Wg = (const float4*)(W + (size_t)r * DIM * DIM);
        float4* Wl4 = (float4*)Wl;
        #pragma unroll
        for (int i = 0; i < 16; ++i)
            Wl4[t + i * 256] = Wg[t + i * 256];
    }
    __syncthreads();
    unsigned short* dst = Wfrag + (size_t)r * DIM * DIM;
    #pragma unroll
    for (int it = 0; it < 8; ++it) {
        const int id = t + it * 256;            // 0..2047
        const int lane = id & 63;
        const int h    = (id >> 6) & 1;
        const int wv   = (id >> 7) & 3;
        const int kk   = (id >> 9) & 3;
        const int n  = 32 * wv + 16 * h + (lane & 15);
        const int kb = 32 * kk + 8 * (lane >> 4);
        ushort4 lo, hi;
        lo.x = f2bf(Wl[(kb + 0) * DIM + n]);
        lo.y = f2bf(Wl[(kb + 1) * DIM + n]);
        lo.z = f2bf(Wl[(kb + 2) * DIM + n]);
        lo.w = f2bf(Wl[(kb + 3) * DIM + n]);
        hi.x = f2bf(Wl[(kb + 4) * DIM + n]);
        hi.y = f2bf(Wl[(kb + 5) * DIM + n]);
        hi.z = f2bf(Wl[(kb + 6) * DIM + n]);
        hi.w = f2bf(Wl[(kb + 7) * DIM + n]);
        *(ushort4*)&dst[id * 8]     = lo;
        *(ushort4*)&dst[id * 8 + 4] = hi;
    }
}

// ---------------------------------------------------------------------------
// K2: fused scans (2 blocks x 1024 thr). Block 0: rel hist -> offsets[461],
// cursor init cur_rel. Block 1: dst hist -> dst_off[4097], cursor cur_dst.
// ---------------------------------------------------------------------------
__global__ void k_scan_both(const int* __restrict__ hist_rel, int* __restrict__ offsets,
                            int* __restrict__ cur_rel,
                            const int* __restrict__ hist_dst, int* __restrict__ dst_off,
                            int* __restrict__ cur_dst)
{
    __shared__ int s[1024];
    const int t = threadIdx.x;
    if (blockIdx.x == 0) {
        const int h = (t < R2) ? hist_rel[t] : 0;
        if (t < 512) s[t] = h;
        __syncthreads();
        for (int off = 1; off < 512; off <<= 1) {
            int a = (t >= off && t < 512) ? s[t - off] : 0;
            __syncthreads();
            if (t < 512) s[t] += a;
            __syncthreads();
        }
        if (t == 0) offsets[0] = 0;
        if (t < R2) {
            offsets[t + 1] = s[t];      // inclusive
            cur_rel[t] = s[t] - h;      // exclusive
        }
    } else {
        const int base = t * 4;
        int v0 = hist_dst[base], v1 = hist_dst[base + 1];
        int v2 = hist_dst[base + 2], v3 = hist_dst[base + 3];
        s[t] = v0 + v1 + v2 + v3;
        __syncthreads();
        for (int off = 1; off < 1024; off <<= 1) {
            int a = (t >= off) ? s[t - off] : 0;
            __syncthreads();
            s[t] += a;
            __syncthreads();
        }
        int run = (t > 0) ? s[t - 1] : 0;
        dst_off[base] = run; cur_dst[base] = run; run += v0;
        dst_off[base + 1] = run; cur_dst[base + 1] = run; run += v1;
        dst_off[base + 2] = run; cur_dst[base + 2] = run; run += v2;
        dst_off[base + 3] = run; cur_dst[base + 3] = run; run += v3;
        if (t == 1023) dst_off[4096] = run;
    }
}

// ---------------------------------------------------------------------------
// K3: scatter. rel-sorted neighbor order; rankpack[i] = row | (rel<<17);
// dst-sorted edge list stores the SOURCE NEIGHBOR ID directly.
// ---------------------------------------------------------------------------
__global__ void k_scatter(const int* __restrict__ rel,
                          int* __restrict__ cur_rel, int* __restrict__ order,
                          int* __restrict__ rankpack,
                          const int* __restrict__ psrc, const int* __restrict__ pdst,
                          int* __restrict__ cur_dst, int* __restrict__ eorder_src) {
    int i = blockIdx.x * blockDim.x + threadIdx.x;
    if (i < N_NBR) {
        const int r = rel[i];
        const int pos = atomicAdd(&cur_rel[r], 1);
        order[pos] = i;
        rankpack[i] = pos | (r << 17);
    }
    if (i < E_EDGE) {
        eorder_src[atomicAdd(&cur_dst[pdst[i]], 1)] = psrc[i];
    }
}

// ---------------------------------------------------------------------------
// K4: MFMA matvec. ONE BLOCK (512 thr = 8 waves) PER RELATION; the 8 waves
// process TWO 64-row chunks concurrently (half = wid>>2). X gathered as bf16
// into swizzled LDS [2][64][128] (32 KB). B-frags read from fragment-ordered
// Wfrag (coalesced 16B/lane, L2-hot). BN stats accumulate in registers,
// cross-half combine via LDS; block emits per-(rel,col) packed float2
// {scale,shift} to global. z_s stored as BF16 (half the write traffic).
// ---------------------------------------------------------------------------
__global__ __launch_bounds__(512, 4) void k_matvec(
    const int* __restrict__ order, const int* __restrict__ offsets,
    const int* __restrict__ nbr,
    const float* __restrict__ years, const float* __restrict__ months, const float* __restrict__ days,
    const float* __restrict__ ent,
    const float* __restrict__ yf, const float* __restrict__ yp, const float* __restrict__ ya,
    const float* __restrict__ mf, const float* __restrict__ mp, const float* __restrict__ ma,
    const float* __restrict__ df, const float* __restrict__ dp, const float* __restrict__ da,
    const unsigned short* __restrict__ Wfrag, const float* __restrict__ bias,
    const float* __restrict__ gamma, const float* __restrict__ beta,
    unsigned short* __restrict__ z_s, float2* __restrict__ scsh)
{
    const int r     = blockIdx.x;
    const int start = offsets[r];
    const int cnt   = offsets[r + 1] - start;

    __shared__ __align__(16) unsigned short Xl[2][CHUNK * DIM];  // 32 KB
    __shared__ int s_ord[2][CHUNK];
    __shared__ int s_ni[2][CHUNK];
    __shared__ float bnred[8][2][16][2];   // [wid][nt][l15][sum|sq]

    const int t    = threadIdx.x;
    const int wid  = t >> 6;        // 0..7
    const int half = wid >> 2;      // 0,1 : which chunk of the pair
    const int wv   = wid & 3;       // column group
    const int lane = t & 63;
    const int l15  = lane & 15;
    const int g    = lane >> 4;

    const int nn0 = 32 * wv + l15;
    const int nn1 = nn0 + 16;
    const float bv0 = bias[r * DIM + nn0];
    const float bv1 = bias[r * DIM + nn1];

    float lsum0 = 0.f, lsq0 = 0.f, lsum1 = 0.f, lsq1 = 0.f;
    const unsigned short* Wr = Wfrag + (size_t)r * DIM * DIM;

    for (int cbase = 0; cbase < cnt; cbase += 2 * CHUNK) {
        const int hbase = cbase + half * CHUNK;
        const int mcnt  = min(CHUNK, max(0, cnt - hbase));

        if (t < 2 * CHUNK) {
            const int hh = t >> 6;   // half being staged
            const int m  = t & 63;
            const int gb = cbase + hh * CHUNK;
            int o = -1, ni = 0;
            if (gb + m < cnt) { o = order[start + gb + m]; ni = nbr[o]; }
            s_ord[hh][m] = o;
            s_ni[hh][m]  = ni;
        }
        __syncthreads();

        // ---- gather X for this half (256 threads): 4 thr/row
        if (mcnt > 0) {
            const int lt = t & 255;
            const int m = lt >> 2, s = lt & 3;
            const int ni = s_ni[half][m];
            const bool vm = (m < mcnt);
            #pragma unroll
            for (int kk = 0; kk < 6; ++kk) {
                const int d = 4 * (s + 4 * kk);
                float4 e = *(const float4*)(ent + (size_t)ni * S_DIM + d);
                ushort4 b;
                b.x = vm ? f2bf(e.x) : 0; b.y = vm ? f2bf(e.y) : 0;
                b.z = vm ? f2bf(e.z) : 0; b.w = vm ? f2bf(e.w) : 0;
                *(ushort4*)&Xl[half][XIDX(m, d)] = b;
            }
            const int o = s_ord[half][m] < 0 ? 0 : s_ord[half][m];
            const float yr = years[o], mo = months[o], dy = days[o];
            #pragma unroll
            for (int hh = 0; hh < 2; ++hh) {
                const int j0 = s * 8 + hh * 4;
                const size_t tb = (size_t)ni * T_DIM + j0;
                const float4 vyf = *(const float4*)(yf + tb), vyp = *(const float4*)(yp + tb), vya = *(const float4*)(ya + tb);
                const float4 vmf = *(const float4*)(mf + tb), vmp = *(const float4*)(mp + tb), vma = *(const float4*)(ma + tb);
                const float4 vdf = *(const float4*)(df + tb), vdp = *(const float4*)(dp + tb), vda = *(const float4*)(da + tb);
                ushort4 b;
                #pragma unroll
                for (int j = 0; j < 4; ++j) {
                    const float fy = ((const float*)&vyf)[j] * yr + ((const float*)&vyp)[j];
                    const float fm = ((const float*)&vmf)[j] * mo + ((const float*)&vmp)[j];
                    const float fd = ((const float*)&vdf)[j] * dy + ((const float*)&vdp)[j];
                    float v = ((const float*)&vya)[j] * sinf(fy)
                            + ((const float*)&vma)[j] * sinf(fm)
                            + ((const float*)&vda)[j] * sinf(fd);
                    ((unsigned short*)&b)[j] = vm ? f2bf(v) : 0;
                }
                *(ushort4*)&Xl[half][XIDX(m, S_DIM + j0)] = b;
            }
        }
        __syncthreads();

        // ---- MFMA + epilogue for this half
        if (mcnt > 0) {
            f32x4 acc[4][2];
            #pragma unroll
            for (int i = 0; i < 4; ++i)
                #pragma unroll
                for (int j = 0; j < 2; ++j) acc[i][j] = (f32x4)0.f;

            #pragma unroll
            for (int kk = 0; kk < 4; ++kk) {
                const int k0 = kk * 32;
                bf16x8 a[4];
                #pragma unroll
                for (int mt = 0; mt < 4; ++mt)
                    a[mt] = *(const bf16x8*)&Xl[half][XIDX(16 * mt + l15, k0 + 8 * g)];
                const bf16x8 b0 = *(const bf16x8*)&Wr[(size_t)((kk * 4 + wv) * 2 + 0) * 512 + lane * 8];
                const bf16x8 b1 = *(const bf16x8*)&Wr[(size_t)((kk * 4 + wv) * 2 + 1) * 512 + lane * 8];
                #pragma unroll
                for (int mt = 0; mt < 4; ++mt) {
                    acc[mt][0] = __builtin_amdgcn_mfma_f32_16x16x32_bf16(a[mt], b0, acc[mt][0], 0, 0, 0);
                    acc[mt][1] = __builtin_amdgcn_mfma_f32_16x16x32_bf16(a[mt], b1, acc[mt][1], 0, 0, 0);
                }
            }

            #pragma unroll
            for (int mt = 0; mt < 4; ++mt) {
                #pragma unroll
                for (int reg = 0; reg < 4; ++reg) {
                    const int ml = 16 * mt + 4 * g + reg;
                    if (ml < mcnt) {
                        const float v0 = acc[mt][0][reg] + bv0;
                        const float v1 = acc[mt][1][reg] + bv1;
                        const size_t row = (size_t)(start + hbase + ml) * DIM;
                        z_s[row + nn0] = f2bf(v0);
                        z_s[row + nn1] = f2bf(v1);
                        lsum0 += v0; lsq0 += v0 * v0;
                        lsum1 += v1; lsq1 += v1 * v1;
                    }
                }
            }
        }
        __syncthreads();
    }

    // ---- BN fold: intra-wave (over g), then cross-half via LDS -> global
    lsum0 += __shfl_xor(lsum0, 16); lsum0 += __shfl_xor(lsum0, 32);
    lsq0  += __shfl_xor(lsq0, 16);  lsq0  += __shfl_xor(lsq0, 32);
    lsum1 += __shfl_xor(lsum1, 16); lsum1 += __shfl_xor(lsum1, 32);
    lsq1  += __shfl_xor(lsq1, 16);  lsq1  += __shfl_xor(lsq1, 32);
    if (g == 0) {
        bnred[wid][0][l15][0] = lsum0; bnred[wid][0][l15][1] = lsq0;
        bnred[wid][1][l15][0] = lsum1; bnred[wid][1][l15][1] = lsq1;
    }
    __syncthreads();
    if (half == 0 && g == 0) {
        #pragma unroll
        for (int nt = 0; nt < 2; ++nt) {
            const int col = 32 * wv + 16 * nt + l15;
            const float s = bnred[wid][nt][l15][0] + bnred[wid + 4][nt][l15][0];
            const float q = bnred[wid][nt][l15][1] + bnred[wid + 4][nt][l15][1];
            float sc = 1.f, sh = 0.f;
            if (cnt > 1) {
                const float mean = s / (float)cnt;
                const float var  = fmaxf(q / (float)cnt - mean * mean, 0.f);
                const int gi = r * DIM + col;
                sc = gamma[gi] * rsqrtf(var + BN_EPS);
                sh = beta[gi] - mean * sc;
            }
            scsh[r * DIM + col] = make_float2(sc, sh);
        }
    }
}

// ---------------------------------------------------------------------------
// K5: pooling with fused BN affine + ReLU. One block per query; chain:
// eorder_src[e] -> rankpack -> {bf16 z_s row, packed scale/shift (L2-hot)}.
// ---------------------------------------------------------------------------
__global__ void k_pool2(const int* __restrict__ eorder_src, const int* __restrict__ dst_off,
                        const int* __restrict__ rankpack,
                        const unsigned short* __restrict__ z_s,
                        const float2* __restrict__ scsh,
                        float* __restrict__ emb)
{
    const int q = blockIdx.x;
    const int d = threadIdx.x;
    const int e0 = dst_off[q], e1 = dst_off[q + 1];
    float acc = 0.f;
    for (int e = e0; e < e1; ++e) {
        const int pk = rankpack[eorder_src[e]];
        const int p  = pk & 0x1FFFF;
        const int r  = pk >> 17;
        const float2 ss = scsh[r * DIM + d];
        const float v = bf2f(z_s[(size_t)p * DIM + d]) * ss.x + ss.y;
        acc += fmaxf(v, 0.f);
    }
    emb[(size_t)q * DIM + d] = (e1 > e0) ? acc / (float)(e1 - e0) : 0.f;
}

// ---------------------------------------------------------------------------
// K6: TransE scoring
// ---------------------------------------------------------------------------
__global__ void k_score(const int* __restrict__ head, const int* __restrict__ tail,
                        const int* __restrict__ rels,
                        const float* __restrict__ emb, const float* __restrict__ rel_embs,
                        float* __restrict__ out)
{
    const int b = blockIdx.x;
    const int d = threadIdx.x;
    const int h = head[b], tq = tail[b], r = rels[b];

    const float diff = emb[(size_t)h * DIM + d] + rel_embs[r * DIM + d]
                     - emb[(size_t)tq * DIM + d];
    float sq = diff * diff;
    for (int off = 32; off > 0; off >>= 1) sq += __shfl_down(sq, off);
    __shared__ float partial[2];
    if ((threadIdx.x & 63) == 0) partial[threadIdx.x >> 6] = sq;
    __syncthreads();
    if (threadIdx.x == 0) out[b] = -sqrtf(partial[0] + partial[1]);
}

// ---------------------------------------------------------------------------
extern "C" void kernel_launch(void* const* d_in, const int* in_sizes, int n_in,
                              void* d_out, int out_size, void* d_ws, size_t ws_size,
                              hipStream_t stream) {
    const int*   neighbor_idx = (const int*)  d_in[0];
    const int*   rel_id       = (const int*)  d_in[1];
    const float* years        = (const float*)d_in[2];
    const float* months       = (const float*)d_in[3];
    const float* days         = (const float*)d_in[4];
    const int*   pool_src     = (const int*)  d_in[5];
    const int*   pool_dst     = (const int*)  d_in[6];
    const int*   head_pos     = (const int*)  d_in[7];
    const int*   tail_pos     = (const int*)  d_in[8];
    const int*   rels         = (const int*)  d_in[9];
    const float* ent_embs     = (const float*)d_in[10];
    const float* y_freq       = (const float*)d_in[11];
    const float* y_phi        = (const float*)d_in[12];
    const float* y_amp        = (const float*)d_in[13];
    const float* m_freq       = (const float*)d_in[14];
    const float* m_phi        = (const float*)d_in[15];
    const float* m_amp        = (const float*)d_in[16];
    const float* d_freq       = (const float*)d_in[17];
    const float* d_phi        = (const float*)d_in[18];
    const float* d_amp        = (const float*)d_in[19];
    const float* rel_embs     = (const float*)d_in[20];
    const float* W            = (const float*)d_in[21];
    const float* bias         = (const float*)d_in[22];
    const float* gamma        = (const float*)d_in[23];
    const float* beta         = (const float*)d_in[24];

    float* out = (float*)d_out;

    // workspace layout (float units)
    float* ws = (float*)d_ws;
    size_t off = 0;
    unsigned short* Wfrag = (unsigned short*)(ws + off); off += (size_t)R2 * DIM * DIM / 2;  // 15 MB
    unsigned short* z_s   = (unsigned short*)(ws + off); off += (size_t)N_NBR * DIM / 2;     // 8 MB
    float* emb   = ws + off; off += (size_t)Q_ENT * DIM;
    float2* scsh = (float2*)(ws + off); off += (size_t)R2 * DIM * 2;
    int* hist_rel = (int*)(ws + off); off += R2;       // zero region (4556 ints)
    int* hist_dst = (int*)(ws + off); off += Q_ENT;
    int* offsets  = (int*)(ws + off); off += R2 + 1;
    int* cur_rel  = (int*)(ws + off); off += R2;
    int* dst_off  = (int*)(ws + off); off += Q_ENT + 1;
    int* cur_dst  = (int*)(ws + off); off += Q_ENT;
    int* order    = (int*)(ws + off); off += N_NBR;
    int* rankpack = (int*)(ws + off); off += N_NBR;
    int* eorder_src = (int*)(ws + off); off += E_EDGE;

    const int nzero4 = (R2 + Q_ENT + 3) / 4;   // 1139 int4
    k_zero<<<(nzero4 + 255) / 256, 256, 0, stream>>>(hist_rel, nzero4);

    k_front<<<R2 + (N_NBR + 255) / 256, 256, 0, stream>>>(
        W, Wfrag, rel_id, pool_dst, hist_rel, hist_dst);

    k_scan_both<<<2, 1024, 0, stream>>>(hist_rel, offsets, cur_rel,
                                        hist_dst, dst_off, cur_dst);

    k_scatter<<<(N_NBR + 255) / 256, 256, 0, stream>>>(rel_id, cur_rel, order, rankpack,
                                                       pool_src, pool_dst, cur_dst, eorder_src);

    k_matvec<<<R2, 512, 0, stream>>>(order, offsets, neighbor_idx,
                                     years, months, days, ent_embs,
                                     y_freq, y_phi, y_amp,
                                     m_freq, m_phi, m_amp,
                                     d_freq, d_phi, d_amp,
                                     Wfrag, bias, gamma, beta,
                                     z_s, scsh);

    k_pool2<<<Q_ENT, DIM, 0, stream>>>(eorder_src, dst_off, rankpack,
                                       z_s, scsh, emb);

    k_score<<<B_TRI, DIM, 0, stream>>>(head_pos, tail_pos, rels, emb, rel_embs, out);
}